// Round 11
// baseline (618.232 us; speedup 1.0000x reference)
//
#include <hip/hip_runtime.h>
#include <hip/hip_bf16.h>
#include <stdint.h>

#define N_NODES 100000
#define N_EDGES 1000000
#define N_GRAPHS 512
#define HID 64
#define INN 32
#define INE 16
#define CPAD 32   // counters padded to 1 per 128 B line

typedef unsigned int uint32;
typedef unsigned short ushort16;
typedef __attribute__((ext_vector_type(8))) short bf8;
typedef __attribute__((ext_vector_type(4))) float f32x4;

__device__ __forceinline__ ushort16 f2bf(float f) {
    uint32 u = __float_as_uint(f);
    uint32 r = (u + 0x7fffu + ((u >> 16) & 1u)) >> 16;  // RNE
    return (ushort16)r;
}
__device__ __forceinline__ uint32 pack_bf2(float lo, float hi) {
    return (uint32)f2bf(lo) | ((uint32)f2bf(hi) << 16);
}
__device__ __forceinline__ float bf_lo(uint32 v) { return __uint_as_float(v << 16); }
__device__ __forceinline__ float bf_hi(uint32 v) { return __uint_as_float(v & 0xffff0000u); }

// ---------------- diag ----------------

__global__ void k_diag(float* out, float val) { out[threadIdx.x] = val; }

// ---------------- CSR build (padded counters) ----------------

__global__ void k_hist(const int* __restrict__ dst, int* __restrict__ counts) {
    int e = blockIdx.x * 256 + threadIdx.x;
    if (e < N_EDGES) atomicAdd(&counts[(size_t)dst[e] * CPAD], 1);
}

__global__ void k_scan1(const int* __restrict__ counts, int* __restrict__ bsums) {
    __shared__ int sdata[256];
    int b = blockIdx.x;
    int s = 0;
    for (int j = threadIdx.x; j < 1024; j += 256) {
        int i = b * 1024 + j;
        s += (i < N_NODES) ? counts[(size_t)i * CPAD] : 0;
    }
    sdata[threadIdx.x] = s; __syncthreads();
    for (int off = 128; off > 0; off >>= 1) {
        if (threadIdx.x < off) sdata[threadIdx.x] += sdata[threadIdx.x + off];
        __syncthreads();
    }
    if (threadIdx.x == 0) bsums[b] = sdata[0];
}

__global__ void k_scan2(int* __restrict__ bsums, int nb) {
    __shared__ int sh[128];
    int v = (threadIdx.x < nb) ? bsums[threadIdx.x] : 0;
    sh[threadIdx.x] = v; __syncthreads();
    for (int off = 1; off < 128; off <<= 1) {
        int t = (threadIdx.x >= off) ? sh[threadIdx.x - off] : 0;
        __syncthreads();
        sh[threadIdx.x] += t;
        __syncthreads();
    }
    if (threadIdx.x < nb) bsums[threadIdx.x] = sh[threadIdx.x] - v;  // exclusive
}

// in-place: reads counts[i*CPAD], writes cursor (same array) + rowptr
__global__ void k_scan3(int* __restrict__ counts_cursor, const int* __restrict__ bsums,
                        int* __restrict__ rowptr) {
    __shared__ int sh[256];
    int b = blockIdx.x;
    int base = b * 1024;
    int v[4]; int s = 0;
    #pragma unroll
    for (int j = 0; j < 4; j++) {
        int i = base + threadIdx.x * 4 + j;
        v[j] = (i < N_NODES) ? counts_cursor[(size_t)i * CPAD] : 0;
        s += v[j];
    }
    sh[threadIdx.x] = s; __syncthreads();
    for (int off = 1; off < 256; off <<= 1) {
        int t = (threadIdx.x >= off) ? sh[threadIdx.x - off] : 0;
        __syncthreads();
        sh[threadIdx.x] += t;
        __syncthreads();
    }
    int excl = sh[threadIdx.x] - s + bsums[b];
    #pragma unroll
    for (int j = 0; j < 4; j++) {
        int i = base + threadIdx.x * 4 + j;
        if (i < N_NODES) {
            rowptr[i] = excl;
            counts_cursor[(size_t)i * CPAD] = excl;  // becomes cursor
            excl += v[j];
        }
    }
    if (b == gridDim.x - 1 && threadIdx.x == 255) rowptr[N_NODES] = excl;
}

// newpos only (perm_src scatter moved into k_edge_mlp_mfma flush)
__global__ void k_fill(const int* __restrict__ dst, int* __restrict__ cursor,
                       int* __restrict__ newpos) {
    int e = blockIdx.x * 256 + threadIdx.x;
    if (e < N_EDGES) {
        int d = dst[e];
        newpos[e] = atomicAdd(&cursor[(size_t)d * CPAD], 1);
    }
}

// ---------------- node-side MLP2 via MFMA ----------------
// BF_IN: input rows packed bf16 (32 uints/row). Residual (RELU_RES) reads bf16 hprev_bf.
// out (f32) nullable — only the final layer materializes f32. Layouts verified R8/R9.

template<int K0, bool RELU_RES, bool BF_IN>
__global__ __launch_bounds__(256, 3) void k_mlp_mfma(
    const void* __restrict__ in, const uint32* __restrict__ hprev_bf,
    float* __restrict__ out,
    const float* __restrict__ w0, const float* __restrict__ b0,
    const float* __restrict__ w1, const float* __restrict__ b1,
    uint32* __restrict__ out_bf, int nrows)
{
    constexpr int NF = K0 / 32;
    __shared__ ushort tile[4][16 * 72];
    const int wave = threadIdx.x >> 6, lane = threadIdx.x & 63;
    const int quad = lane >> 4, mn = lane & 15;
    ushort* T = &tile[wave][0];

    bf8 w0f[4][NF];
    #pragma unroll
    for (int t = 0; t < 4; t++)
        #pragma unroll
        for (int f = 0; f < NF; f++)
            #pragma unroll
            for (int j = 0; j < 8; j++) {
                int k = f * 32 + quad * 8 + j;
                w0f[t][f][j] = (short)f2bf(w0[k * HID + t * 16 + mn]);
            }
    bf8 w1f[4][2];
    #pragma unroll
    for (int t = 0; t < 4; t++)
        #pragma unroll
        for (int f = 0; f < 2; f++)
            #pragma unroll
            for (int j = 0; j < 8; j++) {
                int k = f * 32 + quad * 8 + j;
                w1f[t][f][j] = (short)f2bf(w1[k * HID + t * 16 + mn]);
            }
    float b0v[4], b1v[4];
    #pragma unroll
    for (int t = 0; t < 4; t++) { b0v[t] = b0[t*16+mn]; b1v[t] = b1[t*16+mn]; }

    const int ebase = blockIdx.x * 64 + wave * 16;
    int rowA = ebase + mn; if (rowA > nrows - 1) rowA = nrows - 1;
    bf8 a1[NF];
    if (BF_IN) {
        const ushort* row = (const ushort*)in + (size_t)rowA * HID;
        #pragma unroll
        for (int f = 0; f < NF; f++)
            a1[f] = *(const bf8*)(row + f * 32 + quad * 8);
    } else {
        const float* inf = (const float*)in;
        #pragma unroll
        for (int f = 0; f < NF; f++) {
            const float4* pr = (const float4*)(inf + (size_t)rowA * K0 + f * 32 + quad * 8);
            float4 v0 = pr[0], v1 = pr[1];
            a1[f][0]=(short)f2bf(v0.x); a1[f][1]=(short)f2bf(v0.y);
            a1[f][2]=(short)f2bf(v0.z); a1[f][3]=(short)f2bf(v0.w);
            a1[f][4]=(short)f2bf(v1.x); a1[f][5]=(short)f2bf(v1.y);
            a1[f][6]=(short)f2bf(v1.z); a1[f][7]=(short)f2bf(v1.w);
        }
    }
    #pragma unroll
    for (int t = 0; t < 4; t++) {
        f32x4 c = {0.f, 0.f, 0.f, 0.f};
        #pragma unroll
        for (int f = 0; f < NF; f++)
            c = __builtin_amdgcn_mfma_f32_16x16x32_bf16(a1[f], w0f[t][f], c, 0, 0, 0);
        #pragma unroll
        for (int rg = 0; rg < 4; rg++) {
            int row = quad * 4 + rg;
            T[row * 72 + t * 16 + mn] = f2bf(fmaxf(c[rg] + b0v[t], 0.f));
        }
    }
    __syncthreads();
    bf8 a2[2];
    #pragma unroll
    for (int f = 0; f < 2; f++)
        a2[f] = *(const bf8*)&T[mn * 72 + f * 32 + quad * 8];
    #pragma unroll
    for (int t = 0; t < 4; t++) {
        f32x4 c = {0.f, 0.f, 0.f, 0.f};
        c = __builtin_amdgcn_mfma_f32_16x16x32_bf16(a2[0], w1f[t][0], c, 0, 0, 0);
        c = __builtin_amdgcn_mfma_f32_16x16x32_bf16(a2[1], w1f[t][1], c, 0, 0, 0);
        #pragma unroll
        for (int rg = 0; rg < 4; rg++) {
            int row = quad * 4 + rg;
            int rowg = ebase + row;
            int rowc = (rowg < nrows) ? rowg : (nrows - 1);
            float v = c[rg] + b1v[t];
            if (RELU_RES) {
                uint32 hp = hprev_bf[(size_t)rowc * 32 + ((t * 16 + mn) >> 1)];
                float hv = (mn & 1) ? bf_hi(hp) : bf_lo(hp);
                v = fmaxf(v + hv, 0.f);
            }
            if (out && rowg < nrows) out[(size_t)rowg * HID + t * 16 + mn] = v;
            T[row * 72 + t * 16 + mn] = f2bf(v);
        }
    }
    if (out_bf) {
        __syncthreads();
        int half = lane >> 5, c32 = lane & 31;
        #pragma unroll
        for (int rr = 0; rr < 8; rr++) {
            int row = rr * 2 + half;
            int pos = ebase + row;
            if (pos < nrows) {
                uint32 lo = T[row * 72 + c32 * 2];
                uint32 hi = T[row * 72 + c32 * 2 + 1];
                out_bf[(size_t)pos * 32 + c32] = lo | (hi << 16);
            }
        }
    }
}

// ---------------- edge MLP2 via MFMA; flush also scatters perm_src ----------------

__global__ __launch_bounds__(256, 4) void k_edge_mlp_mfma(
    const float* __restrict__ eattr, const int* __restrict__ newpos,
    const int* __restrict__ src, int* __restrict__ perm_src,
    uint32* __restrict__ e_sorted,
    const float* __restrict__ w0, const float* __restrict__ b0,
    const float* __restrict__ w1, const float* __restrict__ b1)
{
    __shared__ ushort tile[4][16 * 72];
    const int wave = threadIdx.x >> 6, lane = threadIdx.x & 63;
    const int quad = lane >> 4, mn = lane & 15;
    ushort* T = &tile[wave][0];

    bf8 w0f[4];  // layer1 B-frags (K=16 zero-padded to 32)
    #pragma unroll
    for (int t = 0; t < 4; t++) {
        #pragma unroll
        for (int j = 0; j < 8; j++) {
            int k = quad * 8 + j;
            float v = (k < INE) ? w0[k * HID + t * 16 + mn] : 0.f;
            w0f[t][j] = (short)f2bf(v);
        }
    }
    bf8 w1f[4][2];
    #pragma unroll
    for (int t = 0; t < 4; t++)
        #pragma unroll
        for (int f = 0; f < 2; f++)
            #pragma unroll
            for (int j = 0; j < 8; j++) {
                int k = f * 32 + quad * 8 + j;
                w1f[t][f][j] = (short)f2bf(w1[k * HID + t * 16 + mn]);
            }
    float b0v[4], b1v[4];
    #pragma unroll
    for (int t = 0; t < 4; t++) { b0v[t] = b0[t*16+mn]; b1v[t] = b1[t*16+mn]; }

    const int nChunks = N_EDGES / 64;  // 15625 (exact)
    for (int chunk = blockIdx.x; chunk < nChunks; chunk += gridDim.x) {
        const int ebase = chunk * 64 + wave * 16;
        bf8 a1 = {};
        if (quad < 2) {
            const float4* pr = (const float4*)(eattr + (size_t)(ebase + mn) * INE + quad * 8);
            float4 v0 = pr[0], v1 = pr[1];
            a1[0]=(short)f2bf(v0.x); a1[1]=(short)f2bf(v0.y);
            a1[2]=(short)f2bf(v0.z); a1[3]=(short)f2bf(v0.w);
            a1[4]=(short)f2bf(v1.x); a1[5]=(short)f2bf(v1.y);
            a1[6]=(short)f2bf(v1.z); a1[7]=(short)f2bf(v1.w);
        }
        #pragma unroll
        for (int t = 0; t < 4; t++) {
            f32x4 c = {0.f, 0.f, 0.f, 0.f};
            c = __builtin_amdgcn_mfma_f32_16x16x32_bf16(a1, w0f[t], c, 0, 0, 0);
            #pragma unroll
            for (int rg = 0; rg < 4; rg++) {
                int row = quad * 4 + rg;
                T[row * 72 + t * 16 + mn] = f2bf(fmaxf(c[rg] + b0v[t], 0.f));
            }
        }
        __syncthreads();
        bf8 a2[2];
        #pragma unroll
        for (int f = 0; f < 2; f++)
            a2[f] = *(const bf8*)&T[mn * 72 + f * 32 + quad * 8];
        #pragma unroll
        for (int t = 0; t < 4; t++) {
            f32x4 c = {0.f, 0.f, 0.f, 0.f};
            c = __builtin_amdgcn_mfma_f32_16x16x32_bf16(a2[0], w1f[t][0], c, 0, 0, 0);
            c = __builtin_amdgcn_mfma_f32_16x16x32_bf16(a2[1], w1f[t][1], c, 0, 0, 0);
            #pragma unroll
            for (int rg = 0; rg < 4; rg++) {
                int row = quad * 4 + rg;
                T[row * 72 + t * 16 + mn] = f2bf(c[rg] + b1v[t]);
            }
        }
        __syncthreads();
        int half = lane >> 5, c32 = lane & 31;
        #pragma unroll
        for (int rr = 0; rr < 8; rr++) {
            int row = rr * 2 + half;
            int drow = newpos[ebase + row];
            uint32 lo = T[row * 72 + c32 * 2];
            uint32 hi = T[row * 72 + c32 * 2 + 1];
            e_sorted[(size_t)drow * 32 + c32] = lo | (hi << 16);
            if (c32 == 0) perm_src[drow] = src[ebase + row];
        }
        __syncthreads();
    }
}

// ------- GINE aggregation: z = sum relu(h[src]+e) + 1.1*h -> packed bf16 z -------
// self-term from h_bf (bf16) — f32 h no longer read here.

__global__ __launch_bounds__(256, 4) void k_agg(
    const uint32* __restrict__ h_bf, const uint32* __restrict__ e_sorted,
    const int* __restrict__ rowptr, const int* __restrict__ perm_src,
    uint32* __restrict__ z_bf)
{
    int node = blockIdx.x * 4 + (threadIdx.x >> 6);
    if (node >= N_NODES) return;
    int lane = threadIdx.x & 63;
    int half = lane >> 5, c = lane & 31;
    int r0 = rowptr[node], r1 = rowptr[node + 1];
    uint32 hn = h_bf[(size_t)node * 32 + c];  // early issue (broadcast within half-pair)
    float accx = 0.f, accy = 0.f;
    #pragma unroll 1
    for (int base = r0; base < r1; base += 16) {
        int idxs[8]; int sidx[8];
        #pragma unroll
        for (int j = 0; j < 8; j++) {
            int idx = base + 2*j + half;
            idxs[j] = idx;
            int idxc = (idx < r1) ? idx : (r1 - 1);
            sidx[j] = perm_src[idxc];
        }
        uint32 hv[8], ev[8];
        #pragma unroll
        for (int j = 0; j < 8; j++) {
            int idxc = (idxs[j] < r1) ? idxs[j] : (r1 - 1);
            hv[j] = h_bf[(size_t)sidx[j] * 32 + c];
            ev[j] = e_sorted[(size_t)idxc * 32 + c];
        }
        #pragma unroll
        for (int j = 0; j < 8; j++) {
            float mx = fmaxf(bf_lo(hv[j]) + bf_lo(ev[j]), 0.f);
            float my = fmaxf(bf_hi(hv[j]) + bf_hi(ev[j]), 0.f);
            if (idxs[j] < r1) { accx += mx; accy += my; }
        }
    }
    accx += __shfl_xor(accx, 32);
    accy += __shfl_xor(accy, 32);
    if (half == 0) {
        float rx = fmaf(1.1f, bf_lo(hn), accx);
        float ry = fmaf(1.1f, bf_hi(hn), accy);
        z_bf[(size_t)node * 32 + c] = pack_bf2(rx, ry);
    }
}

// ---------------- global add pool (batch is sorted) ----------------

__global__ __launch_bounds__(256) void k_pool(
    const float* __restrict__ h, const int* __restrict__ batch, float* __restrict__ out)
{
    int g = blockIdx.x;
    int lane = threadIdx.x & 63, wave = threadIdx.x >> 6;
    int lo = 0, hi = N_NODES;
    while (lo < hi) { int mid = (lo + hi) >> 1; if (batch[mid] < g) lo = mid + 1; else hi = mid; }
    int start = lo;
    hi = N_NODES;
    while (lo < hi) { int mid = (lo + hi) >> 1; if (batch[mid] < g + 1) lo = mid + 1; else hi = mid; }
    int end = lo;
    float acc = 0.f;
    for (int n = start + wave; n < end; n += 4)
        acc += h[(size_t)n*HID + lane];
    __shared__ float sh[4][64];
    sh[wave][lane] = acc;
    __syncthreads();
    if (wave == 0)
        out[(size_t)g*HID + lane] = sh[0][lane] + sh[1][lane] + sh[2][lane] + sh[3][lane];
}

// ---------------- launch ----------------

extern "C" void kernel_launch(void* const* d_in, const int* in_sizes, int n_in,
                              void* d_out, int out_size, void* d_ws, size_t ws_size,
                              hipStream_t stream) {
    const float* x     = (const float*)d_in[0];
    const int*   eidx  = (const int*)  d_in[1];
    const float* eattr = (const float*)d_in[2];
    const int*   batch = (const int*)  d_in[3];
    const float* wn0 = (const float*)d_in[4];  const float* bn0 = (const float*)d_in[5];
    const float* wn1 = (const float*)d_in[6];  const float* bn1 = (const float*)d_in[7];
    const float* we0 = (const float*)d_in[8];  const float* be0 = (const float*)d_in[9];
    const float* we1 = (const float*)d_in[10]; const float* be1 = (const float*)d_in[11];
    const float* cw0 = (const float*)d_in[12]; const float* cb0 = (const float*)d_in[13];
    const float* cw1 = (const float*)d_in[14]; const float* cb1 = (const float*)d_in[15];
    const float* lw0 = (const float*)d_in[16]; const float* lb0 = (const float*)d_in[17];
    const float* lw1 = (const float*)d_in[18]; const float* lb1 = (const float*)d_in[19];
    const int* src = eidx;
    const int* dst = eidx + N_EDGES;

    // workspace layout (~200 MB)
    char* ws = (char*)d_ws;
    size_t off = 0;
    auto alloc = [&](size_t bytes) -> void* {
        void* p = ws + off;
        off = (off + bytes + 255) & ~(size_t)255;
        return p;
    };
    int*   cc       = (int*)  alloc((size_t)N_NODES * CPAD * 4);  // counts -> cursor
    int*   rowptr   = (int*)  alloc((size_t)(N_NODES + 1) * 4);
    int*   bsums    = (int*)  alloc(128 * 4);
    int*   perm_src = (int*)  alloc((size_t)N_EDGES * 4);
    int*   newpos   = (int*)  alloc((size_t)N_EDGES * 4);
    float* h        = (float*)alloc((size_t)N_NODES * HID * 4);
    uint32* z_bf    = (uint32*)alloc((size_t)N_NODES * 32 * 4);
    uint32* h_bf    = (uint32*)alloc((size_t)N_NODES * 32 * 4);
    uint32* e_sorted = (uint32*)alloc((size_t)N_EDGES * HID * 2);
    if (off > ws_size) {
        k_diag<<<1, 64, 0, stream>>>((float*)d_out, 1.0e9f);
        return;
    }

    const int NB = (N_NODES + 1023) / 1024;  // 98

    hipMemsetAsync(cc, 0, (size_t)N_NODES * CPAD * 4, stream);
    k_hist<<<(N_EDGES + 255) / 256, 256, 0, stream>>>(dst, cc);
    k_scan1<<<NB, 256, 0, stream>>>(cc, bsums);
    k_scan2<<<1, 128, 0, stream>>>(bsums, NB);
    k_scan3<<<NB, 256, 0, stream>>>(cc, bsums, rowptr);
    k_fill<<<(N_EDGES + 255) / 256, 256, 0, stream>>>(dst, cc, newpos);

    const int MGRID = (N_NODES + 63) / 64;  // 1563

    // node init MLP: x (f32) -> h_bf only
    k_mlp_mfma<INN, false, false><<<MGRID, 256, 0, stream>>>(x, nullptr, nullptr,
                                                             wn0, bn0, wn1, bn1,
                                                             h_bf, N_NODES);

    // edge MLP via MFMA -> e_sorted + perm_src (dst-sorted order)
    k_edge_mlp_mfma<<<1024, 256, 0, stream>>>(eattr, newpos, src, perm_src, e_sorted,
                                              we0, be0, we1, be1);

    const int AGRID = (N_NODES + 3) / 4;  // 25000
    for (int l = 0; l < 3; l++) {
        k_agg<<<AGRID, 256, 0, stream>>>(h_bf, e_sorted, rowptr, perm_src, z_bf);
        k_mlp_mfma<HID, true, true><<<MGRID, 256, 0, stream>>>(z_bf, h_bf, nullptr,
                                                               cw0 + l * 4096, cb0 + l * 64,
                                                               cw1 + l * 4096, cb1 + l * 64,
                                                               h_bf, N_NODES);
    }
    // final GINE conv: f32 h materialized once for the pool
    k_agg<<<AGRID, 256, 0, stream>>>(h_bf, e_sorted, rowptr, perm_src, z_bf);
    k_mlp_mfma<HID, false, true><<<MGRID, 256, 0, stream>>>(z_bf, nullptr, h,
                                                            lw0, lb0, lw1, lb1,
                                                            nullptr, N_NODES);

    // global add pool
    k_pool<<<N_GRAPHS, 256, 0, stream>>>(h, batch, (float*)d_out);
}